// Round 5
// baseline (319.796 us; speedup 1.0000x reference)
//
#include <hip/hip_runtime.h>
#include <hip/hip_bf16.h>

// MultiHeadBatchedMixers, fused single-pass:
//   per (b,h,k) block: loop 4 e-slabs of 128:
//     MFMA1: T1 = X @ W1t_slab^T     (A=X global bf16, B=W1t global bf16)
//     MFMA2: T2 = W1c @ T1 + B1      (A=T1^T via wave-private LDS, B=W1c f32)
//     GELU -> H-slab in LDS [64c x 128e]
//     MFMA3: T3 += H_slab @ W2t_slab^T  (A=H LDS, B=W2t global bf16)
//   then T3 relayout (LDS, aliased), MFMA4: out^T = T3^T @ W2c^T, epilogue
//   out[co][n] += wk*(acc4 + B2) via atomicAdd (2 commutative adds/elem -> deterministic)
// Prepack: w1t,w2t,x,b1,b2 -> bf16 ws (single kernel). bf16 MFMA 16x16x32, f32 accum.

namespace {
constexpr int NHEAD = 12, NTOK = 256, HDIM = 64, HIDD = 512, NBATCH = 32, TOPK = 2;
constexpr int NCHAIN = NBATCH * NHEAD * TOPK;  // 768
constexpr int ESLAB = 128, NSLAB = HIDD / ESLAB;  // 4 slabs

// LDS layout (bytes)
constexpr int P_T1 = HDIM * 2 + 16;     // 144 (pitch; 36 words == 4 mod 32 -> ~2-way)
constexpr int T1_W = 32 * P_T1;         // 4608 per wave
constexpr int SM_T1 = 0;                // 4 waves -> [0, 18432)
constexpr int SM_H  = 4 * T1_W;         // 18432
constexpr int P_H   = ESLAB * 2 + 16;   // 272 (68 words == 4 mod 32)
constexpr int SM_H_END = SM_H + HDIM * P_H;  // 18432 + 17408 = 35840
constexpr int P_T3 = HDIM * 2 + 16;     // 144
constexpr int T3_W = 64 * P_T3;         // 9216 per wave
constexpr int SM_T3 = 0;                // aliases T1+H (barrier-protected)
constexpr int SM_TOTAL = 4 * T3_W;      // 36864  (> SM_H_END)

// ws segments (bf16 elements, contiguous in prepack order)
constexpr size_t SZ_W1T = (size_t)8 * NHEAD * HIDD * NTOK;   // 12,582,912
constexpr size_t SZ_W2T = (size_t)8 * NHEAD * NTOK * HIDD;   // 12,582,912
constexpr size_t SZ_X   = (size_t)NBATCH * NHEAD * HDIM * NTOK;  // 6,291,456
constexpr size_t SZ_B1  = (size_t)8 * NHEAD * HDIM * HIDD;   // 3,145,728
constexpr size_t SZ_B2  = (size_t)8 * NHEAD * HDIM * NTOK;   // 1,572,864
constexpr size_t OFF_W1T = 0;
constexpr size_t OFF_W2T = OFF_W1T + SZ_W1T;
constexpr size_t OFF_X   = OFF_W2T + SZ_W2T;
constexpr size_t OFF_B1  = OFF_X + SZ_X;
constexpr size_t OFF_B2  = OFF_B1 + SZ_B1;
constexpr size_t TOTEL   = OFF_B2 + SZ_B2;   // 36,175,872
constexpr size_t NEED    = TOTEL * 2;        // 72.35 MB
}

typedef float f32x4 __attribute__((ext_vector_type(4)));
typedef short bf16x8 __attribute__((ext_vector_type(8)));
typedef short bf16x4 __attribute__((ext_vector_type(4)));

#define MFMA16(a, b, c) __builtin_amdgcn_mfma_f32_16x16x32_bf16((a), (b), (c), 0, 0, 0)

__device__ __forceinline__ short f2bf(float f) {
  union { float f; unsigned u; } v; v.f = f;
  unsigned r = v.u + 0x7fffu + ((v.u >> 16) & 1u);
  return (short)(r >> 16);
}

__device__ __forceinline__ bf16x8 ld_gfrag(const float* p) {
  float4 a = *(const float4*)p;
  float4 b = *(const float4*)(p + 4);
  bf16x8 r;
  r[0] = f2bf(a.x); r[1] = f2bf(a.y); r[2] = f2bf(a.z); r[3] = f2bf(a.w);
  r[4] = f2bf(b.x); r[5] = f2bf(b.y); r[6] = f2bf(b.z); r[7] = f2bf(b.w);
  return r;
}

__device__ __forceinline__ f32x4 bf4f(bf16x4 v) {
  f32x4 r;
  #pragma unroll
  for (int i = 0; i < 4; ++i) {
    union { unsigned u; float f; } t;
    t.u = ((unsigned)(unsigned short)v[i]) << 16;
    r[i] = t.f;
  }
  return r;
}

__device__ __forceinline__ float gelu_tanh(float x) {
  float u = 0.7978845608028654f * x * (1.0f + 0.044715f * x * x);
  return x / (1.0f + __expf(-2.0f * u));
}

// ---------------- Prepack: f32 -> bf16, contiguous segments ----------------
__global__ void prepack_kernel(const float* __restrict__ w1t, const float* __restrict__ w2t,
                               const float* __restrict__ x, const float* __restrict__ b1,
                               const float* __restrict__ b2, short* __restrict__ ws) {
  const size_t C1 = SZ_W1T / 8, C2 = C1 + SZ_W2T / 8, C3 = C2 + SZ_X / 8,
               C4 = C3 + SZ_B1 / 8, C5 = C4 + SZ_B2 / 8;
  for (size_t i = (size_t)blockIdx.x * blockDim.x + threadIdx.x; i < C5;
       i += (size_t)gridDim.x * blockDim.x) {
    const float* s;
    if (i < C1)      s = w1t + i * 8;
    else if (i < C2) s = w2t + (i - C1) * 8;
    else if (i < C3) s = x   + (i - C2) * 8;
    else if (i < C4) s = b1  + (i - C3) * 8;
    else             s = b2  + (i - C4) * 8;
    *((bf16x8*)ws + i) = ld_gfrag(s);  // segments are contiguous in ws in same order
  }
}

// ---------------- Fused mixer ----------------
// grid = 768 (one block per chain bhk), 4 waves.
// Wave roles: stage1 (per slab): wave w owns e-local rows [w*32, w*32+32).
//             stage3: wave w owns n in [w*64, w*64+64), all 64 c.
template <bool PP>
__global__ __launch_bounds__(256) void mixer_fused(
    const float* __restrict__ xf32, const int* __restrict__ eidx, const float* __restrict__ ewt,
    const float* __restrict__ w1t, const float* __restrict__ w1c, const float* __restrict__ b1,
    const float* __restrict__ w2t, const float* __restrict__ w2c, const float* __restrict__ b2,
    const short* __restrict__ ws, float* __restrict__ out) {
  __shared__ __align__(16) char smem[SM_TOTAL];
  const int bhk = blockIdx.x;
  const int bh = bhk >> 1;
  const int h = bh % NHEAD;
  const int tid = threadIdx.x, w = tid >> 6, lane = tid & 63, lr = lane & 15, lg = lane >> 4;

  const int e = eidx[bhk];
  const float wk = ewt[bhk];
  const size_t eh = (size_t)e * NHEAD + h;

  const short* Xb   = ws + OFF_X   + (size_t)bh * HDIM * NTOK;
  const short* W1Tb = ws + OFF_W1T + eh * HIDD * NTOK;
  const short* B1b  = ws + OFF_B1  + eh * HDIM * HIDD;
  const short* W2Tb = ws + OFF_W2T + eh * NTOK * HIDD;
  const short* B2b  = ws + OFF_B2  + eh * HDIM * NTOK;
  const float* Xf   = xf32 + (size_t)bh * HDIM * NTOK;
  const float* W1Tf = w1t + eh * HIDD * NTOK;
  const float* B1f  = b1  + eh * HDIM * HIDD;
  const float* W2Tf = w2t + eh * NTOK * HIDD;
  const float* B2f  = b2  + eh * HDIM * NTOK;
  const float* W1C  = w1c + eh * HDIM * HDIM;
  const float* W2C  = w2c + eh * HDIM * HDIM;

  char* t1 = smem + SM_T1 + w * T1_W;
  char* Hs = smem + SM_H;

  f32x4 acc3[4][4];  // [ct][nt], persists across slabs
  #pragma unroll
  for (int ct = 0; ct < 4; ++ct)
    #pragma unroll
    for (int nt = 0; nt < 4; ++nt) acc3[ct][nt] = (f32x4){0.f, 0.f, 0.f, 0.f};

  for (int t = 0; t < NSLAB; ++t) {
    const int e0 = t * ESLAB + w * 32;

    // ---- MFMA1: T1[d][e] = sum_n X[d,n]*W1t[e,n];  D: col=e=lr, row=d=lg*4+i ----
    f32x4 acc1[2][4];
    #pragma unroll
    for (int et = 0; et < 2; ++et)
      #pragma unroll
      for (int dt = 0; dt < 4; ++dt) acc1[et][dt] = (f32x4){0.f, 0.f, 0.f, 0.f};
    #pragma unroll
    for (int ks = 0; ks < 8; ++ks) {
      bf16x8 w0, w1v;
      if (PP) {
        w0  = *(const bf16x8*)(W1Tb + (size_t)(e0 + lr) * NTOK + ks * 32 + lg * 8);
        w1v = *(const bf16x8*)(W1Tb + (size_t)(e0 + 16 + lr) * NTOK + ks * 32 + lg * 8);
      } else {
        w0  = ld_gfrag(W1Tf + (size_t)(e0 + lr) * NTOK + ks * 32 + lg * 8);
        w1v = ld_gfrag(W1Tf + (size_t)(e0 + 16 + lr) * NTOK + ks * 32 + lg * 8);
      }
      #pragma unroll
      for (int dt = 0; dt < 4; ++dt) {
        bf16x8 xfr;
        if (PP) xfr = *(const bf16x8*)(Xb + (size_t)(dt * 16 + lr) * NTOK + ks * 32 + lg * 8);
        else    xfr = ld_gfrag(Xf + (size_t)(dt * 16 + lr) * NTOK + ks * 32 + lg * 8);
        acc1[0][dt] = MFMA16(xfr, w0, acc1[0][dt]);
        acc1[1][dt] = MFMA16(xfr, w1v, acc1[1][dt]);
      }
    }

    // ---- T1^T relayout via wave-private LDS: t1[e-local][d] ----
    #pragma unroll
    for (int et = 0; et < 2; ++et)
      #pragma unroll
      for (int dt = 0; dt < 4; ++dt) {
        bf16x4 p;
        #pragma unroll
        for (int i = 0; i < 4; ++i) p[i] = f2bf(acc1[et][dt][i]);
        *(bf16x4*)(t1 + (et * 16 + lr) * P_T1 + (dt * 16 + lg * 4) * 2) = p;
      }

    // ---- MFMA2: T2^T[e][c] = sum_d T1^T[e,d]*W1c[c,d] + B1;  D: col=c=lr, row=e=lg*4+i ----
    f32x4 acc2[2][4];
    #pragma unroll
    for (int et = 0; et < 2; ++et)
      #pragma unroll
      for (int ct = 0; ct < 4; ++ct) {
        if (PP) {
          bf16x4 bb = *(const bf16x4*)(B1b + (size_t)(ct * 16 + lr) * HIDD + e0 + et * 16 + lg * 4);
          acc2[et][ct] = bf4f(bb);
        } else {
          acc2[et][ct] = *(const f32x4*)(B1f + (size_t)(ct * 16 + lr) * HIDD + e0 + et * 16 + lg * 4);
        }
      }
    #pragma unroll
    for (int ks = 0; ks < 2; ++ks) {
      bf16x8 a[2];
      #pragma unroll
      for (int et = 0; et < 2; ++et)
        a[et] = *(const bf16x8*)(t1 + (et * 16 + lr) * P_T1 + (ks * 32 + lg * 8) * 2);
      #pragma unroll
      for (int ct = 0; ct < 4; ++ct) {
        bf16x8 bfr = ld_gfrag(W1C + (size_t)(ct * 16 + lr) * HDIM + ks * 32 + lg * 8);
        #pragma unroll
        for (int et = 0; et < 2; ++et) acc2[et][ct] = MFMA16(a[et], bfr, acc2[et][ct]);
      }
    }

    // ---- GELU + H-slab store: Hs[c][e-local], e-local = w*32 + et*16 + lg*4+i ----
    #pragma unroll
    for (int et = 0; et < 2; ++et)
      #pragma unroll
      for (int ct = 0; ct < 4; ++ct) {
        bf16x4 g;
        #pragma unroll
        for (int i = 0; i < 4; ++i) g[i] = f2bf(gelu_tanh(acc2[et][ct][i]));
        *(bf16x4*)(Hs + (ct * 16 + lr) * P_H + (w * 32 + et * 16 + lg * 4) * 2) = g;
      }
    __syncthreads();

    // ---- MFMA3: T3[c][n] += sum_e H[c,e]*W2t[n,e];  wave owns n in [w*64, +64) ----
    #pragma unroll
    for (int ks = 0; ks < 4; ++ks) {
      bf16x8 a[4];
      #pragma unroll
      for (int ct = 0; ct < 4; ++ct)
        a[ct] = *(const bf16x8*)(Hs + (ct * 16 + lr) * P_H + (ks * 32 + lg * 8) * 2);
      #pragma unroll
      for (int nt = 0; nt < 4; ++nt) {
        bf16x8 bfr;
        if (PP) bfr = *(const bf16x8*)(W2Tb + (size_t)(w * 64 + nt * 16 + lr) * HIDD + t * ESLAB + ks * 32 + lg * 8);
        else    bfr = ld_gfrag(W2Tf + (size_t)(w * 64 + nt * 16 + lr) * HIDD + t * ESLAB + ks * 32 + lg * 8);
        #pragma unroll
        for (int ct = 0; ct < 4; ++ct) acc3[ct][nt] = MFMA16(a[ct], bfr, acc3[ct][nt]);
      }
    }
    __syncthreads();  // protect H-slab (and T1 region) before next slab / T3 alias
  }

  // ---- T3^T relayout (region aliases T1+H; all reads barrier-complete) ----
  char* t3 = smem + SM_T3 + w * T3_W;
  #pragma unroll
  for (int ct = 0; ct < 4; ++ct)
    #pragma unroll
    for (int nt = 0; nt < 4; ++nt) {
      bf16x4 p;
      #pragma unroll
      for (int i = 0; i < 4; ++i) p[i] = f2bf(acc3[ct][nt][i]);
      *(bf16x4*)(t3 + (nt * 16 + lr) * P_T3 + (ct * 16 + lg * 4) * 2) = p;
    }

  // ---- MFMA4: OUT^T[n][co] = sum_c T3^T[n,c]*W2c[co,c];  D: col=co=lr, row=n=lg*4+i ----
  f32x4 acc4[4][4];  // [nt][cot]
  #pragma unroll
  for (int nt = 0; nt < 4; ++nt)
    #pragma unroll
    for (int cot = 0; cot < 4; ++cot) acc4[nt][cot] = (f32x4){0.f, 0.f, 0.f, 0.f};
  #pragma unroll
  for (int ks = 0; ks < 2; ++ks) {
    bf16x8 wf[4];
    #pragma unroll
    for (int cot = 0; cot < 4; ++cot)
      wf[cot] = ld_gfrag(W2C + (size_t)(cot * 16 + lr) * HDIM + ks * 32 + lg * 8);
    #pragma unroll
    for (int nt = 0; nt < 4; ++nt) {
      bf16x8 a = *(const bf16x8*)(t3 + (nt * 16 + lr) * P_T3 + (ks * 32 + lg * 8) * 2);
      #pragma unroll
      for (int cot = 0; cot < 4; ++cot) acc4[nt][cot] = MFMA16(a, wf[cot], acc4[nt][cot]);
    }
  }

  // ---- epilogue: out[co][n] += wk*(acc4 + B2), 2 commutative atomics/element ----
  float* OUT = out + (size_t)bh * HDIM * NTOK;
  #pragma unroll
  for (int nt = 0; nt < 4; ++nt)
    #pragma unroll
    for (int cot = 0; cot < 4; ++cot) {
      const int co = cot * 16 + lr;
      const int n0 = w * 64 + nt * 16 + lg * 4;
      f32x4 bb;
      if (PP) bb = bf4f(*(const bf16x4*)(B2b + (size_t)co * NTOK + n0));
      else    bb = *(const f32x4*)(B2f + (size_t)co * NTOK + n0);
      float* op = OUT + (size_t)co * NTOK + n0;
      #pragma unroll
      for (int i = 0; i < 4; ++i) atomicAdd(op + i, wk * (acc4[nt][cot][i] + bb[i]));
    }
}

extern "C" void kernel_launch(void* const* d_in, const int* in_sizes, int n_in,
                              void* d_out, int out_size, void* d_ws, size_t ws_size,
                              hipStream_t stream) {
  const float* x   = (const float*)d_in[0];
  const int*   ei  = (const int*)d_in[1];
  const float* ew  = (const float*)d_in[2];
  const float* w1t = (const float*)d_in[3];
  const float* w1c = (const float*)d_in[4];
  const float* b1  = (const float*)d_in[5];
  const float* w2t = (const float*)d_in[6];
  const float* w2c = (const float*)d_in[7];
  const float* b2  = (const float*)d_in[8];
  float* out = (float*)d_out;
  short* ws = (short*)d_ws;

  hipMemsetAsync(out, 0, (size_t)out_size * sizeof(float), stream);

  if (ws_size >= NEED) {
    prepack_kernel<<<dim3(2048), dim3(256), 0, stream>>>(w1t, w2t, x, b1, b2, ws);
    mixer_fused<true><<<dim3(NCHAIN), dim3(256), 0, stream>>>(
        x, ei, ew, w1t, w1c, b1, w2t, w2c, b2, ws, out);
  } else {
    mixer_fused<false><<<dim3(NCHAIN), dim3(256), 0, stream>>>(
        x, ei, ew, w1t, w1c, b1, w2t, w2c, b2, ws, out);
  }
}